// Round 2
// 1187.118 us; speedup vs baseline: 1.1185x; 1.1185x over previous
//
#include <hip/hip_runtime.h>

// MultiLoraLinear: y = x@W^T + bias + (x@A^T)@Bw^T (per-segment adapter, scale=1)
// M=16384 (8x2048), K=4096, N=4096, r=16.
// bf16-cast + MFMA NT-GEMM. Main GEMM is the 256x256 8-phase template
// (T1 XCD swizzle + T2 LDS XOR swizzle + T3/T4 counted-vmcnt phases + T5 setprio).
// LoRA folded in as one extra K=32 tile (u = x@A^T; Bw padded to 32 cols).

typedef __attribute__((ext_vector_type(8))) short short8;
typedef __attribute__((ext_vector_type(4))) float f32x4;
typedef __attribute__((ext_vector_type(4))) unsigned short u16x4;
typedef unsigned short u16;

typedef __attribute__((address_space(1))) void as1_void;
typedef __attribute__((address_space(3))) void as3_void;

#define M_DIM 16384
#define N_DIM 4096
#define K_DIM 4096
#define K2 8192  // K_DIM * sizeof(bf16) bytes per row
#define BM 256
#define BN 256
#define BK 64

__device__ __forceinline__ u16 f2bf(float f) {
  union { float f; unsigned u; } v; v.f = f;
  unsigned r = (v.u + 0x7FFFu + ((v.u >> 16) & 1u)) >> 16;  // RNE
  return (u16)r;
}
__device__ __forceinline__ float bf2f(u16 u) {
  union { unsigned u; float f; } v; v.u = ((unsigned)u) << 16;
  return v.f;
}
__device__ __forceinline__ void gload16(const void* g, void* lds) {
  // async global->LDS, 16B/lane; LDS dest = wave-uniform base + lane*16
  __builtin_amdgcn_global_load_lds((as1_void*)g, (as3_void*)lds, 16, 0, 0);
}
__device__ __forceinline__ int seg_of_batch(const int* starts, int b) {
  int seg = -1;
#pragma unroll
  for (int i = 0; i < 4; ++i) seg += (starts[i] <= b) ? 1 : 0;
  return seg;  // 0 = no LoRA; adapter = clamp(seg-1, 0, 2)
}

#define VMCNT(n) asm volatile("s_waitcnt vmcnt(" #n ")" ::: "memory")

// ---------------- prep: fp32 -> bf16 casts + padded Bw ----------------
__global__ __launch_bounds__(256) void prep_kernel(
    const float* __restrict__ x, const float* __restrict__ wgt,
    const float* __restrict__ lA, const float* __restrict__ lB,
    u16* __restrict__ xbf, u16* __restrict__ wbf,
    u16* __restrict__ abf, u16* __restrict__ bw) {
  const long long NX4 = 16777216LL;  // 67108864/4
  const long long NW4 = 4194304LL;   // 16777216/4
  const long long NA4 = 49152LL;     // 196608/4
  const long long NB  = 12288LL;     // 3*4096 (a,n) rows of lora_B
  const long long total = NX4 + NW4 + NA4 + NB;
  const f32x4* x4 = (const f32x4*)x;
  const f32x4* w4 = (const f32x4*)wgt;
  const f32x4* a4 = (const f32x4*)lA;
  u16x4* xo = (u16x4*)xbf;
  u16x4* wo = (u16x4*)wbf;
  u16x4* ao = (u16x4*)abf;
  for (long long i = (long long)blockIdx.x * blockDim.x + threadIdx.x; i < total;
       i += (long long)gridDim.x * blockDim.x) {
    if (i < NX4) {
      f32x4 v = x4[i];
      u16x4 o = {f2bf(v.x), f2bf(v.y), f2bf(v.z), f2bf(v.w)};
      xo[i] = o;
    } else if (i < NX4 + NW4) {
      long long j = i - NX4;
      f32x4 v = w4[j];
      u16x4 o = {f2bf(v.x), f2bf(v.y), f2bf(v.z), f2bf(v.w)};
      wo[j] = o;
    } else if (i < NX4 + NW4 + NA4) {
      long long j = i - NX4 - NW4;
      f32x4 v = a4[j];
      u16x4 o = {f2bf(v.x), f2bf(v.y), f2bf(v.z), f2bf(v.w)};
      ao[j] = o;
    } else {
      long long p = i - NX4 - NW4 - NA4;  // flat (a*4096+n)
      const float* src = lB + p * 16;
      u16* dst = bw + p * 32;
#pragma unroll
      for (int j = 0; j < 16; ++j) dst[j] = f2bf(src[j]);
#pragma unroll
      for (int j = 16; j < 32; ++j) dst[j] = 0;
    }
  }
}

// ---------------- u = x @ A^T  -> bf16 [M][32], zero-padded ----------------
__global__ __launch_bounds__(256) void ucompute_kernel(
    const u16* __restrict__ xbf, const u16* __restrict__ abf,
    const int* __restrict__ starts, u16* __restrict__ u) {
  const int l = threadIdx.x & 63;
  const int w = threadIdx.x >> 6;
  const int mbase = blockIdx.x * 16 + w * 4;
  const int b = mbase >> 11;  // /2048
  const int seg = seg_of_batch(starts, b);
  const int use = seg > 0;
  int ad = seg - 1; ad = ad < 0 ? 0 : (ad > 2 ? 2 : ad);

  float acc[4][16];
#pragma unroll
  for (int row = 0; row < 4; ++row)
#pragma unroll
    for (int r = 0; r < 16; ++r) acc[row][r] = 0.f;

  if (use) {
    const u16* xr = xbf + (size_t)mbase * K_DIM + l * 8;
    const u16* ar = abf + (size_t)ad * (16 * K_DIM) + l * 8;
    for (int pass = 0; pass < 8; ++pass) {
      const int off = pass * 512;
      float xv[4][8];
#pragma unroll
      for (int row = 0; row < 4; ++row) {
        short8 xs = *(const short8*)(xr + (size_t)row * K_DIM + off);
#pragma unroll
        for (int j = 0; j < 8; ++j) xv[row][j] = bf2f((u16)xs[j]);
      }
#pragma unroll
      for (int r = 0; r < 16; ++r) {
        short8 av = *(const short8*)(ar + (size_t)r * K_DIM + off);
#pragma unroll
        for (int j = 0; j < 8; ++j) {
          float a = bf2f((u16)av[j]);
#pragma unroll
          for (int row = 0; row < 4; ++row) acc[row][r] += xv[row][j] * a;
        }
      }
    }
  }
#pragma unroll
  for (int row = 0; row < 4; ++row) {
    float myval = 0.f;
#pragma unroll
    for (int r = 0; r < 16; ++r) {
      float v = acc[row][r];
      v += __shfl_xor(v, 32);
      v += __shfl_xor(v, 16);
      v += __shfl_xor(v, 8);
      v += __shfl_xor(v, 4);
      v += __shfl_xor(v, 2);
      v += __shfl_xor(v, 1);
      if (l == r) myval = v;  // lane r keeps u[m][r]
    }
    if (l < 32) u[(size_t)(mbase + row) * 32 + l] = (l < 16) ? f2bf(myval) : (u16)0;
  }
}

// ---------------- main NT-GEMM, 256x256 tile, 8-phase schedule ----------------
// 512 threads = 8 waves (2 M-waves x 4 N-waves); each wave owns 128x64 output.
// K-tile = 64. LDS: 2 x (A 32KB + B 32KB) = 128KB double buffer.
// Regions per K-tile (liveness units, 16KB = 2 gload16/thread each):
//   A-ih (ih=0/1): A rows {ih*64..ih*64+63} U {128+ih*64..191+ih*64}
//   B-jh (jh=0/1): B rows {jh*32 + 64c + 128d : c,d in {0,1}} x 32
// Quadrant phases per tile: (ih,jh) = (0,0),(0,1),(1,0),(1,1). A-ih0 dies after
// q(0,1); B-jh0 after q(1,0); A-ih1/B-jh1 after q(1,1). Stage region = tile+2,
// one phase after death. Only waits: vmcnt(4) at phases 4 and 8 (never 0).
// T2 swizzle: physical 16B slot = logical slot ^ (row&7); applied on the
// gload16 *global source* (LDS dest stays linear, rule #21) and on ds_read.

// stage macros: 2 x gload16 covering one 16KB region of tile kt.
#define STAGE_A(buf, ih, kt) do { \
  gload16(aSrc + (size_t)((ih)*64) * K2 + (size_t)(kt)*128, \
          &As[buf][((ih)*64) * BK] + w * 512); \
  gload16(aSrc + (size_t)((ih)*64 + 128) * K2 + (size_t)(kt)*128, \
          &As[buf][((ih)*64 + 128) * BK] + w * 512); \
} while (0)
#define STAGE_B(buf, jh, kt) do { \
  gload16(bSrc + (size_t)((jh)*32) * K2 + (size_t)(kt)*128, \
          &Bs[buf][((jh)*32 + (w >> 2)*64) * BK] + (w & 3) * 512); \
  gload16(bSrc + (size_t)((jh)*32 + 128) * K2 + (size_t)(kt)*128, \
          &Bs[buf][((jh)*32 + (w >> 2)*64 + 128) * BK] + (w & 3) * 512); \
} while (0)

// one phase: 12 ds_read_b128 -> stage -> [wait] -> barrier -> 16 MFMA -> barrier
#define PHASE(buf, ih, jh, STAGE_STMT, WAIT_STMT) do { \
  short8 aF0[4], aF1[4], bF0[2], bF1[2]; \
  _Pragma("unroll") \
  for (int i2 = 0; i2 < 4; ++i2) { \
    const u16* ar = &As[buf][(wr*128 + (ih)*64 + i2*16 + fm) * BK]; \
    aF0[i2] = *(const short8*)(ar + c0); \
    aF1[i2] = *(const short8*)(ar + c1); \
  } \
  _Pragma("unroll") \
  for (int j2 = 0; j2 < 2; ++j2) { \
    const u16* br = &Bs[buf][(wc*64 + (jh)*32 + j2*16 + fm) * BK]; \
    bF0[j2] = *(const short8*)(br + c0); \
    bF1[j2] = *(const short8*)(br + c1); \
  } \
  STAGE_STMT; \
  WAIT_STMT; \
  __builtin_amdgcn_s_barrier(); \
  __builtin_amdgcn_s_setprio(1); \
  _Pragma("unroll") \
  for (int i2 = 0; i2 < 4; ++i2) \
  _Pragma("unroll") \
  for (int j2 = 0; j2 < 2; ++j2) { \
    acc[(ih)*4 + i2][(jh)*2 + j2] = __builtin_amdgcn_mfma_f32_16x16x32_bf16( \
        aF0[i2], bF0[j2], acc[(ih)*4 + i2][(jh)*2 + j2], 0, 0, 0); \
    acc[(ih)*4 + i2][(jh)*2 + j2] = __builtin_amdgcn_mfma_f32_16x16x32_bf16( \
        aF1[i2], bF1[j2], acc[(ih)*4 + i2][(jh)*2 + j2], 0, 0, 0); \
  } \
  __builtin_amdgcn_s_setprio(0); \
  __builtin_amdgcn_s_barrier(); \
} while (0)

__global__ __launch_bounds__(512, 2) void gemm8_kernel(
    const u16* __restrict__ xbf, const u16* __restrict__ wbf,
    const float* __restrict__ bias, const u16* __restrict__ ubuf,
    const u16* __restrict__ bwpad, const int* __restrict__ starts,
    float* __restrict__ out) {
  __shared__ u16 As[2][BM * BK];  // 64 KB
  __shared__ u16 Bs[2][BN * BK];  // 64 KB

  const int tid = threadIdx.x;
  const int l = tid & 63;
  const int w = tid >> 6;

  // T1: bijective XCD swizzle (1024 blocks, 1024 % 8 == 0)
  const int bid = blockIdx.x;
  const int nb = (bid & 7) * 128 + (bid >> 3);
  const int m0 = (nb >> 4) << 8;  // 64 M-tiles
  const int n0 = (nb & 15) << 8;  // 16 N-tiles

  const int b = m0 >> 11;  // block fully inside one batch sample (2048 rows)
  const int seg = seg_of_batch(starts, b);
  int ad = seg - 1; ad = ad < 0 ? 0 : (ad > 2 ? 2 : ad);
  // (no-LoRA blocks: u rows are zero, so the LoRA tile contributes nothing)

  // ---- staging constants: wave w covers 8 consecutive rows per gload16 ----
  const int lrow = l >> 3;                  // row within 8-row chunk
  const int swzslot = (l & 7) ^ lrow;       // pre-swizzled global 16B slot
  const char* aSrc = (const char*)xbf +
      (size_t)(m0 + 8 * w + lrow) * K2 + swzslot * 16;
  const char* bSrc = (const char*)wbf +
      (size_t)(n0 + (w >> 2) * 64 + (w & 3) * 8 + lrow) * K2 + swzslot * 16;

  // ---- fragment-read constants ----
  const int fm = l & 15;
  const int q = l >> 4;
  const int wr = w >> 2;  // 0..1
  const int wc = w & 3;   // 0..3
  const int c0 = ((q ^ (fm & 7)) * 8);        // u16 offset, k-step 0 (swizzled)
  const int c1 = (((q + 4) ^ (fm & 7)) * 8);  // u16 offset, k-step 1

  f32x4 acc[8][4];
  const f32x4 z4 = {0.f, 0.f, 0.f, 0.f};
#pragma unroll
  for (int i = 0; i < 8; ++i)
#pragma unroll
    for (int j = 0; j < 4; ++j) acc[i][j] = z4;

  // ---- prologue: tile0 fully + tile1 A0,B0 (12 loads); leave last 4 in flight
  STAGE_A(0, 0, 0); STAGE_B(0, 0, 0); STAGE_A(0, 1, 0); STAGE_B(0, 1, 0);
  STAGE_A(1, 0, 1); STAGE_B(1, 0, 1);
  VMCNT(4);
  __builtin_amdgcn_s_barrier();

  // ---- main loop: 32 iterations x 2 K-tiles (K = 64 tiles) ----
  for (int s = 0; s < 32; ++s) {
    const int t1 = 2 * s + 1;
    const int t2 = 2 * s + 2;
    const int t3 = 2 * s + 3;
    const bool more = (s < 31);
    PHASE(0, 0, 0, STAGE_A(1, 1, t1), (void)0);
    PHASE(0, 0, 1, STAGE_B(1, 1, t1), (void)0);
    PHASE(0, 1, 0, if (more) STAGE_A(0, 0, t2), (void)0);
    PHASE(0, 1, 1, if (more) STAGE_B(0, 0, t2),
          if (more) VMCNT(4); else VMCNT(0));
    PHASE(1, 0, 0, if (more) STAGE_A(0, 1, t2), (void)0);
    PHASE(1, 0, 1, if (more) STAGE_B(0, 1, t2), (void)0);
    PHASE(1, 1, 0, if (more) STAGE_A(1, 0, t3), (void)0);
    PHASE(1, 1, 1, if (more) STAGE_B(1, 0, t3),
          if (more) VMCNT(4); else VMCNT(0));
  }

  // ---- LoRA K=32 tile: A = u[M][32], B = bwpad[ad][N][32]; into buf0 flat ----
  {
    u16* la = &As[0][0];  // [256][32] packed, 16KB
    u16* lb = &Bs[0][0];
    const int ls = l & 3;  // 16B slot within 64B row
    const int lr = l >> 2; // row within 16-row chunk
    const char* uSrc = (const char*)ubuf +
        (size_t)(m0 + 16 * w + lr) * 64 + ls * 16;
    const char* vSrc = (const char*)bwpad +
        ((size_t)ad * N_DIM + n0 + 16 * w + lr) * 64 + ls * 16;
    gload16(uSrc, la + (16 * w) * 32);
    gload16(uSrc + (size_t)128 * 64, la + (128 + 16 * w) * 32);
    gload16(vSrc, lb + (16 * w) * 32);
    gload16(vSrc + (size_t)128 * 64, lb + (128 + 16 * w) * 32);
    VMCNT(0);
    __builtin_amdgcn_s_barrier();
    short8 aF[8], bF[4];
#pragma unroll
    for (int i = 0; i < 8; ++i)
      aF[i] = *(const short8*)(la + (wr * 128 + i * 16 + fm) * 32 + q * 8);
#pragma unroll
    for (int j = 0; j < 4; ++j)
      bF[j] = *(const short8*)(lb + (wc * 64 + j * 16 + fm) * 32 + q * 8);
#pragma unroll
    for (int i = 0; i < 8; ++i)
#pragma unroll
      for (int j = 0; j < 4; ++j)
        acc[i][j] = __builtin_amdgcn_mfma_f32_16x16x32_bf16(aF[i], bF[j],
                                                            acc[i][j], 0, 0, 0);
  }

  // ---- epilogue: C/D layout col=l&15, row=(l>>4)*4+reg ----
  float bv[4];
#pragma unroll
  for (int j = 0; j < 4; ++j) bv[j] = bias[n0 + wc * 64 + j * 16 + fm];
#pragma unroll
  for (int i = 0; i < 8; ++i) {
#pragma unroll
    for (int ii = 0; ii < 4; ++ii) {
      const int m = m0 + wr * 128 + i * 16 + q * 4 + ii;
      float* orow = out + (size_t)m * N_DIM + n0 + wc * 64 + fm;
#pragma unroll
      for (int j = 0; j < 4; ++j) orow[j * 16] = acc[i][j][ii] + bv[j];
    }
  }
}

// ---------------- fp32 fallback (only if ws_size < fast-path need) ----------------
__global__ __launch_bounds__(256) void u_f32_kernel(
    const float* __restrict__ x, const float* __restrict__ lA,
    const int* __restrict__ starts, float* __restrict__ u) {
  const int l = threadIdx.x & 63;
  const int w = threadIdx.x >> 6;
  const int m = blockIdx.x * 4 + w;
  const int b = m >> 11;
  const int seg = seg_of_batch(starts, b);
  const int use = seg > 0;
  int ad = seg - 1; ad = ad < 0 ? 0 : (ad > 2 ? 2 : ad);
  float acc[16];
#pragma unroll
  for (int r = 0; r < 16; ++r) acc[r] = 0.f;
  if (use) {
    const float* xr = x + (size_t)m * K_DIM + l * 4;
    const float* ar = lA + (size_t)ad * (16 * K_DIM) + l * 4;
    for (int pass = 0; pass < 16; ++pass) {
      const int off = pass * 256;
      f32x4 xv = *(const f32x4*)(xr + off);
#pragma unroll
      for (int r = 0; r < 16; ++r) {
        f32x4 av = *(const f32x4*)(ar + (size_t)r * K_DIM + off);
        acc[r] += xv.x * av.x + xv.y * av.y + xv.z * av.z + xv.w * av.w;
      }
    }
  }
  float myval = 0.f;
#pragma unroll
  for (int r = 0; r < 16; ++r) {
    float v = acc[r];
    v += __shfl_xor(v, 32);
    v += __shfl_xor(v, 16);
    v += __shfl_xor(v, 8);
    v += __shfl_xor(v, 4);
    v += __shfl_xor(v, 2);
    v += __shfl_xor(v, 1);
    if (l == r) myval = v;
  }
  if (l < 16) u[(size_t)m * 16 + l] = myval;
}

__global__ __launch_bounds__(256) void gemm_f32_fallback(
    const float* __restrict__ x, const float* __restrict__ wgt,
    const float* __restrict__ bias, const float* __restrict__ lB,
    const float* __restrict__ u, const int* __restrict__ starts,
    float* __restrict__ out) {
  __shared__ float xs[4096];
  const int m = blockIdx.y;
  const int n0 = blockIdx.x * 256;
  const int t = threadIdx.x;
  const f32x4* xr4 = (const f32x4*)(x + (size_t)m * K_DIM);
  f32x4* xs4 = (f32x4*)xs;
  for (int i = t; i < 1024; i += 256) xs4[i] = xr4[i];
  __syncthreads();
  const int b = m >> 11;
  const int seg = seg_of_batch(starts, b);
  const int use = seg > 0;
  int ad = seg - 1; ad = ad < 0 ? 0 : (ad > 2 ? 2 : ad);
  const int n = n0 + t;
  const f32x4* wr = (const f32x4*)(wgt + (size_t)n * K_DIM);
  float acc = 0.f;
  for (int kk = 0; kk < 1024; ++kk) {
    f32x4 wv = wr[kk];
    f32x4 xv = xs4[kk];
    acc += xv.x * wv.x + xv.y * wv.y + xv.z * wv.z + xv.w * wv.w;
  }
  acc += bias[n];
  if (use) {
    const float* Bn = lB + ((size_t)ad * N_DIM + n) * 16;
    const float* um = u + (size_t)m * 16;
    float lo = 0.f;
#pragma unroll
    for (int r = 0; r < 16; ++r) lo += um[r] * Bn[r];
    acc += lo;
  }
  out[(size_t)m * N_DIM + n] = acc;
}

extern "C" void kernel_launch(void* const* d_in, const int* in_sizes, int n_in,
                              void* d_out, int out_size, void* d_ws, size_t ws_size,
                              hipStream_t stream) {
  const float* x    = (const float*)d_in[0];
  const float* wgt  = (const float*)d_in[1];
  const float* bias = (const float*)d_in[2];
  const float* lA   = (const float*)d_in[3];
  const float* lB   = (const float*)d_in[4];
  const int* starts = (const int*)d_in[5];
  float* out = (float*)d_out;

  const size_t XBF_OFF = 0;                      // 134217728 B
  const size_t WBF_OFF = 134217728;              //  33554432 B
  const size_t ABF_OFF = 167772160;              //    393216 B
  const size_t BW_OFF  = 168165376;              //    786432 B
  const size_t U_OFF   = 168951808;              //   1048576 B
  const size_t WS_NEEDED = 170000384;

  if (ws_size >= WS_NEEDED) {
    u16* xbf = (u16*)((char*)d_ws + XBF_OFF);
    u16* wbf = (u16*)((char*)d_ws + WBF_OFF);
    u16* abf = (u16*)((char*)d_ws + ABF_OFF);
    u16* bw  = (u16*)((char*)d_ws + BW_OFF);
    u16* u   = (u16*)((char*)d_ws + U_OFF);
    prep_kernel<<<8192, 256, 0, stream>>>(x, wgt, lA, lB, xbf, wbf, abf, bw);
    ucompute_kernel<<<1024, 256, 0, stream>>>(xbf, abf, starts, u);
    gemm8_kernel<<<1024, 512, 0, stream>>>(xbf, wbf, bias, u, bw, starts, out);
  } else {
    // fp32 fallback: needs only 1 MB of ws for u
    float* uf = (float*)d_ws;
    u_f32_kernel<<<4096, 256, 0, stream>>>(x, lA, starts, uf);
    gemm_f32_fallback<<<dim3(16, 16384), 256, 0, stream>>>(x, wgt, bias, lB, uf, starts, out);
  }
}

// Round 3
// 1131.622 us; speedup vs baseline: 1.1733x; 1.0490x over previous
//
#include <hip/hip_runtime.h>

// MultiLoraLinear: y = x@W^T + bias + (x@A^T)@Bw^T (per-segment adapter, scale=1)
// M=16384 (8x2048), K=4096, N=4096, r=16.
// bf16-cast + MFMA NT-GEMM. Main GEMM is the 256x256 8-phase template
// (T1 XCD swizzle + T2 LDS XOR swizzle + T3/T4 counted-vmcnt phases + T5 setprio)
// with snake-order register-fragment reuse: 24 ds_read_b128 per K-tile (the
// unique minimum) instead of 48 (round-2 version re-read every fragment twice;
// MfmaUtil was 34% => LDS-read-issue bound).
// LoRA folded in as one extra K=32 tile (u = x@A^T; Bw padded to 32 cols).

typedef __attribute__((ext_vector_type(8))) short short8;
typedef __attribute__((ext_vector_type(4))) float f32x4;
typedef __attribute__((ext_vector_type(4))) unsigned short u16x4;
typedef unsigned short u16;

typedef __attribute__((address_space(1))) void as1_void;
typedef __attribute__((address_space(3))) void as3_void;

#define M_DIM 16384
#define N_DIM 4096
#define K_DIM 4096
#define K2 8192  // K_DIM * sizeof(bf16) bytes per row
#define BM 256
#define BN 256
#define BK 64

__device__ __forceinline__ u16 f2bf(float f) {
  union { float f; unsigned u; } v; v.f = f;
  unsigned r = (v.u + 0x7FFFu + ((v.u >> 16) & 1u)) >> 16;  // RNE
  return (u16)r;
}
__device__ __forceinline__ float bf2f(u16 u) {
  union { unsigned u; float f; } v; v.u = ((unsigned)u) << 16;
  return v.f;
}
__device__ __forceinline__ void gload16(const void* g, void* lds) {
  // async global->LDS, 16B/lane; LDS dest = wave-uniform base + lane*16
  __builtin_amdgcn_global_load_lds((as1_void*)g, (as3_void*)lds, 16, 0, 0);
}
__device__ __forceinline__ int seg_of_batch(const int* starts, int b) {
  int seg = -1;
#pragma unroll
  for (int i = 0; i < 4; ++i) seg += (starts[i] <= b) ? 1 : 0;
  return seg;  // 0 = no LoRA; adapter = clamp(seg-1, 0, 2)
}

#define VMCNT(n) asm volatile("s_waitcnt vmcnt(" #n ")" ::: "memory")

// ---------------- prep: fp32 -> bf16 casts + padded Bw ----------------
__global__ __launch_bounds__(256) void prep_kernel(
    const float* __restrict__ x, const float* __restrict__ wgt,
    const float* __restrict__ lA, const float* __restrict__ lB,
    u16* __restrict__ xbf, u16* __restrict__ wbf,
    u16* __restrict__ abf, u16* __restrict__ bw) {
  const long long NX4 = 16777216LL;  // 67108864/4
  const long long NW4 = 4194304LL;   // 16777216/4
  const long long NA4 = 49152LL;     // 196608/4
  const long long NB  = 12288LL;     // 3*4096 (a,n) rows of lora_B
  const long long total = NX4 + NW4 + NA4 + NB;
  const f32x4* x4 = (const f32x4*)x;
  const f32x4* w4 = (const f32x4*)wgt;
  const f32x4* a4 = (const f32x4*)lA;
  u16x4* xo = (u16x4*)xbf;
  u16x4* wo = (u16x4*)wbf;
  u16x4* ao = (u16x4*)abf;
  for (long long i = (long long)blockIdx.x * blockDim.x + threadIdx.x; i < total;
       i += (long long)gridDim.x * blockDim.x) {
    if (i < NX4) {
      f32x4 v = x4[i];
      u16x4 o = {f2bf(v.x), f2bf(v.y), f2bf(v.z), f2bf(v.w)};
      xo[i] = o;
    } else if (i < NX4 + NW4) {
      long long j = i - NX4;
      f32x4 v = w4[j];
      u16x4 o = {f2bf(v.x), f2bf(v.y), f2bf(v.z), f2bf(v.w)};
      wo[j] = o;
    } else if (i < NX4 + NW4 + NA4) {
      long long j = i - NX4 - NW4;
      f32x4 v = a4[j];
      u16x4 o = {f2bf(v.x), f2bf(v.y), f2bf(v.z), f2bf(v.w)};
      ao[j] = o;
    } else {
      long long p = i - NX4 - NW4 - NA4;  // flat (a*4096+n)
      const float* src = lB + p * 16;
      u16* dst = bw + p * 32;
#pragma unroll
      for (int j = 0; j < 16; ++j) dst[j] = f2bf(src[j]);
#pragma unroll
      for (int j = 16; j < 32; ++j) dst[j] = 0;
    }
  }
}

// ---------------- u = x @ A^T  -> bf16 [M][32], zero-padded ----------------
__global__ __launch_bounds__(256) void ucompute_kernel(
    const u16* __restrict__ xbf, const u16* __restrict__ abf,
    const int* __restrict__ starts, u16* __restrict__ u) {
  const int l = threadIdx.x & 63;
  const int w = threadIdx.x >> 6;
  const int mbase = blockIdx.x * 16 + w * 4;
  const int b = mbase >> 11;  // /2048
  const int seg = seg_of_batch(starts, b);
  const int use = seg > 0;
  int ad = seg - 1; ad = ad < 0 ? 0 : (ad > 2 ? 2 : ad);

  float acc[4][16];
#pragma unroll
  for (int row = 0; row < 4; ++row)
#pragma unroll
    for (int r = 0; r < 16; ++r) acc[row][r] = 0.f;

  if (use) {
    const u16* xr = xbf + (size_t)mbase * K_DIM + l * 8;
    const u16* ar = abf + (size_t)ad * (16 * K_DIM) + l * 8;
    for (int pass = 0; pass < 8; ++pass) {
      const int off = pass * 512;
      float xv[4][8];
#pragma unroll
      for (int row = 0; row < 4; ++row) {
        short8 xs = *(const short8*)(xr + (size_t)row * K_DIM + off);
#pragma unroll
        for (int j = 0; j < 8; ++j) xv[row][j] = bf2f((u16)xs[j]);
      }
#pragma unroll
      for (int r = 0; r < 16; ++r) {
        short8 av = *(const short8*)(ar + (size_t)r * K_DIM + off);
#pragma unroll
        for (int j = 0; j < 8; ++j) {
          float a = bf2f((u16)av[j]);
#pragma unroll
          for (int row = 0; row < 4; ++row) acc[row][r] += xv[row][j] * a;
        }
      }
    }
  }
#pragma unroll
  for (int row = 0; row < 4; ++row) {
    float myval = 0.f;
#pragma unroll
    for (int r = 0; r < 16; ++r) {
      float v = acc[row][r];
      v += __shfl_xor(v, 32);
      v += __shfl_xor(v, 16);
      v += __shfl_xor(v, 8);
      v += __shfl_xor(v, 4);
      v += __shfl_xor(v, 2);
      v += __shfl_xor(v, 1);
      if (l == r) myval = v;  // lane r keeps u[m][r]
    }
    if (l < 32) u[(size_t)(mbase + row) * 32 + l] = (l < 16) ? f2bf(myval) : (u16)0;
  }
}

// ---------------- main NT-GEMM, 256x256 tile, 8-phase schedule ----------------
// 512 threads = 8 waves (2 M-waves x 4 N-waves); each wave owns 128x64 output.
// K-tile = 64. LDS: 2 x (A 32KB + B 32KB) = 128KB double buffer.
// Snake phase order per K-tile: (ih,jh) = (0,0),(0,1),(1,1),(1,0).
//   P1 loads aFr(ih0)+bF0r(jh0) [12 ds_read], P2 loads bF1r(jh1) [4],
//   P3 loads aFr(ih1) [8], P4 loads nothing (reuses aFr+bF0r). 24/tile.
// Every LDS region is read in exactly one phase -> dead immediately after.
// Staging: one 16KB region (2 gload16/thread) per phase; region staged exactly
// one phase after its death; steady-state in-flight depth = 3 regions (6 loads);
// counted VMCNT(6) at P4/P8 only (never 0 in main loop).
// T2 swizzle: physical 16B slot = logical slot ^ (row&7); applied on the
// gload16 *global source* (LDS dest stays linear, rule #21) and on ds_read.

// stage macros: 2 x gload16 covering one 16KB region of tile kt.
#define STAGE_A(buf, ih, kt) do { \
  gload16(aSrc + (size_t)((ih)*64) * K2 + (size_t)(kt)*128, \
          &As[buf][((ih)*64) * BK] + w * 512); \
  gload16(aSrc + (size_t)((ih)*64 + 128) * K2 + (size_t)(kt)*128, \
          &As[buf][((ih)*64 + 128) * BK] + w * 512); \
} while (0)
#define STAGE_B(buf, jh, kt) do { \
  gload16(bSrc + (size_t)((jh)*32) * K2 + (size_t)(kt)*128, \
          &Bs[buf][((jh)*32 + (w >> 2)*64) * BK] + (w & 3) * 512); \
  gload16(bSrc + (size_t)((jh)*32 + 128) * K2 + (size_t)(kt)*128, \
          &Bs[buf][((jh)*32 + (w >> 2)*64 + 128) * BK] + (w & 3) * 512); \
} while (0)

// one phase: [0-12] ds_read_b128 -> stage 1 region -> [wait] -> barrier ->
//            16 MFMA (setprio-wrapped) -> barrier
#define PHASE(buf, ih, jh, LA, LB, BARR, STAGE_STMT, WAIT_STMT) do { \
  if (LA) { \
    _Pragma("unroll") \
    for (int i2 = 0; i2 < 4; ++i2) { \
      const u16* ar = &As[buf][(wr*128 + (ih)*64 + i2*16 + fm) * BK]; \
      aFr[i2][0] = *(const short8*)(ar + c0); \
      aFr[i2][1] = *(const short8*)(ar + c1); \
    } \
  } \
  if (LB) { \
    _Pragma("unroll") \
    for (int j2 = 0; j2 < 2; ++j2) { \
      const u16* br = &Bs[buf][(wc*64 + (jh)*32 + j2*16 + fm) * BK]; \
      BARR[j2][0] = *(const short8*)(br + c0); \
      BARR[j2][1] = *(const short8*)(br + c1); \
    } \
  } \
  STAGE_STMT; \
  WAIT_STMT; \
  __builtin_amdgcn_s_barrier(); \
  __builtin_amdgcn_s_setprio(1); \
  _Pragma("unroll") \
  for (int i2 = 0; i2 < 4; ++i2) \
  _Pragma("unroll") \
  for (int j2 = 0; j2 < 2; ++j2) { \
    acc[(ih)*4 + i2][(jh)*2 + j2] = __builtin_amdgcn_mfma_f32_16x16x32_bf16( \
        aFr[i2][0], BARR[j2][0], acc[(ih)*4 + i2][(jh)*2 + j2], 0, 0, 0); \
    acc[(ih)*4 + i2][(jh)*2 + j2] = __builtin_amdgcn_mfma_f32_16x16x32_bf16( \
        aFr[i2][1], BARR[j2][1], acc[(ih)*4 + i2][(jh)*2 + j2], 0, 0, 0); \
  } \
  __builtin_amdgcn_s_setprio(0); \
  __builtin_amdgcn_s_barrier(); \
} while (0)

__global__ __launch_bounds__(512, 2) void gemm8_kernel(
    const u16* __restrict__ xbf, const u16* __restrict__ wbf,
    const float* __restrict__ bias, const u16* __restrict__ ubuf,
    const u16* __restrict__ bwpad, const int* __restrict__ starts,
    float* __restrict__ out) {
  __shared__ u16 As[2][BM * BK];  // 64 KB
  __shared__ u16 Bs[2][BN * BK];  // 64 KB

  const int tid = threadIdx.x;
  const int l = tid & 63;
  const int w = tid >> 6;

  // T1: bijective XCD swizzle (1024 blocks, 1024 % 8 == 0)
  const int bid = blockIdx.x;
  const int nb = (bid & 7) * 128 + (bid >> 3);
  const int m0 = (nb >> 4) << 8;  // 64 M-tiles
  const int n0 = (nb & 15) << 8;  // 16 N-tiles

  const int b = m0 >> 11;  // block fully inside one batch sample (2048 rows)
  const int seg = seg_of_batch(starts, b);
  int ad = seg - 1; ad = ad < 0 ? 0 : (ad > 2 ? 2 : ad);
  // (no-LoRA blocks: u rows are zero, so the LoRA tile contributes nothing)

  // ---- staging constants: wave w covers 8 consecutive rows per gload16 ----
  const int lrow = l >> 3;                  // row within 8-row chunk
  const int swzslot = (l & 7) ^ lrow;       // pre-swizzled global 16B slot
  const char* aSrc = (const char*)xbf +
      (size_t)(m0 + 8 * w + lrow) * K2 + swzslot * 16;
  const char* bSrc = (const char*)wbf +
      (size_t)(n0 + (w >> 2) * 64 + (w & 3) * 8 + lrow) * K2 + swzslot * 16;

  // ---- fragment-read constants ----
  const int fm = l & 15;
  const int q = l >> 4;
  const int wr = w >> 2;  // 0..1
  const int wc = w & 3;   // 0..3
  const int c0 = ((q ^ (fm & 7)) * 8);        // u16 offset, k-step 0 (swizzled)
  const int c1 = (((q + 4) ^ (fm & 7)) * 8);  // u16 offset, k-step 1

  f32x4 acc[8][4];
  const f32x4 z4 = {0.f, 0.f, 0.f, 0.f};
#pragma unroll
  for (int i = 0; i < 8; ++i)
#pragma unroll
    for (int j = 0; j < 4; ++j) acc[i][j] = z4;

  // persistent register fragments (snake reuse)
  short8 aFr[4][2];   // current ih-half of A, both k-steps
  short8 bF0r[2][2];  // jh=0 half of B
  short8 bF1r[2][2];  // jh=1 half of B

  // ---- prologue: all 4 regions of tile0 (buf0) + 3 regions of tile1 (buf1);
  // VMCNT(6) completes the oldest 8 loads = all of tile0; 3 regions in flight.
  STAGE_A(0, 0, 0); STAGE_B(0, 0, 0); STAGE_B(0, 1, 0); STAGE_A(0, 1, 0);
  STAGE_A(1, 0, 1); STAGE_B(1, 1, 1); STAGE_A(1, 1, 1);
  VMCNT(6);
  __builtin_amdgcn_s_barrier();

  // ---- main loop: 32 iterations x 2 K-tiles (K = 64 tiles) ----
  // Stage targets (one region per phase, staged one phase after region death):
  //  P1: B-jh0(buf1, 2s+1)  [read P5/P8 this iter; region freed at prev P8]
  //  P2: A-ih0(buf0, 2s+2)  P3: B-jh1(buf0)  P4: A-ih1(buf0)  P5: B-jh0(buf0)
  //  P6: A-ih0(buf1, 2s+3)  P7: B-jh1(buf1)  P8: A-ih1(buf1)
  for (int s = 0; s < 32; ++s) {
    const int t1 = 2 * s + 1;
    const int t2 = 2 * s + 2;
    const int t3 = 2 * s + 3;
    const bool more = (s < 31);
    PHASE(0, 0, 0, 1, 1, bF0r, STAGE_B(1, 0, t1), (void)0);
    PHASE(0, 0, 1, 0, 1, bF1r, if (more) STAGE_A(0, 0, t2), (void)0);
    PHASE(0, 1, 1, 1, 0, bF1r, if (more) STAGE_B(0, 1, t2), (void)0);
    PHASE(0, 1, 0, 0, 0, bF0r, if (more) STAGE_A(0, 1, t2),
          if (more) VMCNT(6); else VMCNT(0));
    PHASE(1, 0, 0, 1, 1, bF0r, if (more) STAGE_B(0, 0, t2), (void)0);
    PHASE(1, 0, 1, 0, 1, bF1r, if (more) STAGE_A(1, 0, t3), (void)0);
    PHASE(1, 1, 1, 1, 0, bF1r, if (more) STAGE_B(1, 1, t3), (void)0);
    PHASE(1, 1, 0, 0, 0, bF0r, if (more) STAGE_A(1, 1, t3),
          if (more) VMCNT(6); else VMCNT(0));
  }

  // ---- LoRA K=32 tile: A = u[M][32], B = bwpad[ad][N][32]; into buf0 flat ----
  {
    u16* la = &As[0][0];  // [256][32] packed, 16KB
    u16* lb = &Bs[0][0];
    const int ls = l & 3;  // 16B slot within 64B row
    const int lr = l >> 2; // row within 16-row chunk
    const char* uSrc = (const char*)ubuf +
        (size_t)(m0 + 16 * w + lr) * 64 + ls * 16;
    const char* vSrc = (const char*)bwpad +
        ((size_t)ad * N_DIM + n0 + 16 * w + lr) * 64 + ls * 16;
    gload16(uSrc, la + (16 * w) * 32);
    gload16(uSrc + (size_t)128 * 64, la + (128 + 16 * w) * 32);
    gload16(vSrc, lb + (16 * w) * 32);
    gload16(vSrc + (size_t)128 * 64, lb + (128 + 16 * w) * 32);
    VMCNT(0);
    __builtin_amdgcn_s_barrier();
    short8 aF[8], bF[4];
#pragma unroll
    for (int i = 0; i < 8; ++i)
      aF[i] = *(const short8*)(la + (wr * 128 + i * 16 + fm) * 32 + q * 8);
#pragma unroll
    for (int j = 0; j < 4; ++j)
      bF[j] = *(const short8*)(lb + (wc * 64 + j * 16 + fm) * 32 + q * 8);
#pragma unroll
    for (int i = 0; i < 8; ++i)
#pragma unroll
      for (int j = 0; j < 4; ++j)
        acc[i][j] = __builtin_amdgcn_mfma_f32_16x16x32_bf16(aF[i], bF[j],
                                                            acc[i][j], 0, 0, 0);
  }

  // ---- epilogue: C/D layout col=l&15, row=(l>>4)*4+reg ----
  float bv[4];
#pragma unroll
  for (int j = 0; j < 4; ++j) bv[j] = bias[n0 + wc * 64 + j * 16 + fm];
#pragma unroll
  for (int i = 0; i < 8; ++i) {
#pragma unroll
    for (int ii = 0; ii < 4; ++ii) {
      const int m = m0 + wr * 128 + i * 16 + q * 4 + ii;
      float* orow = out + (size_t)m * N_DIM + n0 + wc * 64 + fm;
#pragma unroll
      for (int j = 0; j < 4; ++j) orow[j * 16] = acc[i][j][ii] + bv[j];
    }
  }
}

// ---------------- fp32 fallback (only if ws_size < fast-path need) ----------------
__global__ __launch_bounds__(256) void u_f32_kernel(
    const float* __restrict__ x, const float* __restrict__ lA,
    const int* __restrict__ starts, float* __restrict__ u) {
  const int l = threadIdx.x & 63;
  const int w = threadIdx.x >> 6;
  const int m = blockIdx.x * 4 + w;
  const int b = m >> 11;
  const int seg = seg_of_batch(starts, b);
  const int use = seg > 0;
  int ad = seg - 1; ad = ad < 0 ? 0 : (ad > 2 ? 2 : ad);
  float acc[16];
#pragma unroll
  for (int r = 0; r < 16; ++r) acc[r] = 0.f;
  if (use) {
    const float* xr = x + (size_t)m * K_DIM + l * 4;
    const float* ar = lA + (size_t)ad * (16 * K_DIM) + l * 4;
    for (int pass = 0; pass < 16; ++pass) {
      const int off = pass * 256;
      f32x4 xv = *(const f32x4*)(xr + off);
#pragma unroll
      for (int r = 0; r < 16; ++r) {
        f32x4 av = *(const f32x4*)(ar + (size_t)r * K_DIM + off);
        acc[r] += xv.x * av.x + xv.y * av.y + xv.z * av.z + xv.w * av.w;
      }
    }
  }
  float myval = 0.f;
#pragma unroll
  for (int r = 0; r < 16; ++r) {
    float v = acc[r];
    v += __shfl_xor(v, 32);
    v += __shfl_xor(v, 16);
    v += __shfl_xor(v, 8);
    v += __shfl_xor(v, 4);
    v += __shfl_xor(v, 2);
    v += __shfl_xor(v, 1);
    if (l == r) myval = v;
  }
  if (l < 16) u[(size_t)m * 16 + l] = myval;
}

__global__ __launch_bounds__(256) void gemm_f32_fallback(
    const float* __restrict__ x, const float* __restrict__ wgt,
    const float* __restrict__ bias, const float* __restrict__ lB,
    const float* __restrict__ u, const int* __restrict__ starts,
    float* __restrict__ out) {
  __shared__ float xs[4096];
  const int m = blockIdx.y;
  const int n0 = blockIdx.x * 256;
  const int t = threadIdx.x;
  const f32x4* xr4 = (const f32x4*)(x + (size_t)m * K_DIM);
  f32x4* xs4 = (f32x4*)xs;
  for (int i = t; i < 1024; i += 256) xs4[i] = xr4[i];
  __syncthreads();
  const int b = m >> 11;
  const int seg = seg_of_batch(starts, b);
  const int use = seg > 0;
  int ad = seg - 1; ad = ad < 0 ? 0 : (ad > 2 ? 2 : ad);
  const int n = n0 + t;
  const f32x4* wr = (const f32x4*)(wgt + (size_t)n * K_DIM);
  float acc = 0.f;
  for (int kk = 0; kk < 1024; ++kk) {
    f32x4 wv = wr[kk];
    f32x4 xv = xs4[kk];
    acc += xv.x * wv.x + xv.y * wv.y + xv.z * wv.z + xv.w * wv.w;
  }
  acc += bias[n];
  if (use) {
    const float* Bn = lB + ((size_t)ad * N_DIM + n) * 16;
    const float* um = u + (size_t)m * 16;
    float lo = 0.f;
#pragma unroll
    for (int r = 0; r < 16; ++r) lo += um[r] * Bn[r];
    acc += lo;
  }
  out[(size_t)m * N_DIM + n] = acc;
}

extern "C" void kernel_launch(void* const* d_in, const int* in_sizes, int n_in,
                              void* d_out, int out_size, void* d_ws, size_t ws_size,
                              hipStream_t stream) {
  const float* x    = (const float*)d_in[0];
  const float* wgt  = (const float*)d_in[1];
  const float* bias = (const float*)d_in[2];
  const float* lA   = (const float*)d_in[3];
  const float* lB   = (const float*)d_in[4];
  const int* starts = (const int*)d_in[5];
  float* out = (float*)d_out;

  const size_t XBF_OFF = 0;                      // 134217728 B
  const size_t WBF_OFF = 134217728;              //  33554432 B
  const size_t ABF_OFF = 167772160;              //    393216 B
  const size_t BW_OFF  = 168165376;              //    786432 B
  const size_t U_OFF   = 168951808;              //   1048576 B
  const size_t WS_NEEDED = 170000384;

  if (ws_size >= WS_NEEDED) {
    u16* xbf = (u16*)((char*)d_ws + XBF_OFF);
    u16* wbf = (u16*)((char*)d_ws + WBF_OFF);
    u16* abf = (u16*)((char*)d_ws + ABF_OFF);
    u16* bw  = (u16*)((char*)d_ws + BW_OFF);
    u16* u   = (u16*)((char*)d_ws + U_OFF);
    prep_kernel<<<8192, 256, 0, stream>>>(x, wgt, lA, lB, xbf, wbf, abf, bw);
    ucompute_kernel<<<1024, 256, 0, stream>>>(xbf, abf, starts, u);
    gemm8_kernel<<<1024, 512, 0, stream>>>(xbf, wbf, bias, u, bw, starts, out);
  } else {
    // fp32 fallback: needs only 1 MB of ws for u
    float* uf = (float*)d_ws;
    u_f32_kernel<<<4096, 256, 0, stream>>>(x, lA, starts, uf);
    gemm_f32_fallback<<<dim3(16, 16384), 256, 0, stream>>>(x, wgt, bias, lB, uf, starts, out);
  }
}